// Round 4
// baseline (334.860 us; speedup 1.0000x reference)
//
#include <hip/hip_runtime.h>
#include <cstdint>
#include <cstddef>

#define T_DIM 256
#define H_DIM 4096
#define I_DIM 14336
// GROUP_SIZE=64 == BK: one (scale,zero) per row per K-tile.

typedef __attribute__((ext_vector_type(8))) short s8v;   // 8 bf16
typedef __attribute__((ext_vector_type(4))) short s4v;   // 4 bf16
typedef __attribute__((ext_vector_type(4))) float f4v;   // MFMA C/D frag

static constexpr size_t XS_BYTES   = (size_t)T_DIM * H_DIM * 2;   // 2 MiB bf16 x
static constexpr size_t ACT_OFF    = XS_BYTES;
static constexpr size_t ACT_BYTES  = (size_t)T_DIM * I_DIM * 2;   // 7.34 MB bf16 act
static constexpr size_t PART_OFF   = ACT_OFF + ACT_BYTES;
static constexpr size_t PART_BYTES = 4ull * T_DIM * H_DIM * 4;    // 16 MiB (4 K-chunks)
static constexpr size_t WS_NEEDED  = PART_OFF + PART_BYTES;

__device__ __forceinline__ unsigned short f2bf(float f) {
    unsigned u = __builtin_bit_cast(unsigned, f);
    u += 0x7fffu + ((u >> 16) & 1u);
    return (unsigned short)(u >> 16);
}

// Barrier discipline: never drain vmcnt in the main loop.
__device__ __forceinline__ void bar_read() {
    __builtin_amdgcn_sched_barrier(0);
    __builtin_amdgcn_s_barrier();
    __builtin_amdgcn_sched_barrier(0);
}
__device__ __forceinline__ void bar_write() {
    __builtin_amdgcn_sched_barrier(0);
    asm volatile("s_waitcnt lgkmcnt(0)" ::: "memory");
    __builtin_amdgcn_s_barrier();
    __builtin_amdgcn_sched_barrier(0);
}

__device__ __forceinline__ s4v dq4(const int4 q, float s, float ns) {
    union { unsigned short u[4]; s4v v; } r;
    r.u[0] = f2bf(fmaf((float)q.x, s, ns));
    r.u[1] = f2bf(fmaf((float)q.y, s, ns));
    r.u[2] = f2bf(fmaf((float)q.z, s, ns));
    r.u[3] = f2bf(fmaf((float)q.w, s, ns));
    return r.v;
}

// ---------------------------------------------------------------------------
// k_prep: x fp32 [256,4096] -> bf16 row-major (flat cast).
// ---------------------------------------------------------------------------
__global__ __launch_bounds__(256) void k_prep(const float* __restrict__ x,
                                              unsigned short* __restrict__ xs) {
    int i = (blockIdx.x * 256 + threadIdx.x) * 8;
    float4 a = *(const float4*)(x + i);
    float4 b = *(const float4*)(x + i + 4);
    union { unsigned short u[8]; s8v v; } r;
    r.u[0] = f2bf(a.x); r.u[1] = f2bf(a.y); r.u[2] = f2bf(a.z); r.u[3] = f2bf(a.w);
    r.u[4] = f2bf(b.x); r.u[5] = f2bf(b.y); r.u[6] = f2bf(b.z); r.u[7] = f2bf(b.w);
    *(s8v*)(xs + i) = r.v;
}

// ---------------------------------------------------------------------------
// k_gemm1: fused gate/up GEMM. BM=256(all M), BN=32, BK=64, K=4096, grid 448.
// 8 waves, each owns 32 M-rows x all 32 N-cols. A (x) read straight from
// global (L2-resident); LDS holds only dequanted weights (2 x 8KB dbuf).
// ---------------------------------------------------------------------------
struct S1 { int4 q1, q3; float s1, z1, s3, z3; };

__global__ __launch_bounds__(512, 4) void k_gemm1(
    const int* __restrict__ w1q, const float* __restrict__ w1s, const float* __restrict__ w1z,
    const int* __restrict__ w3q, const float* __restrict__ w3s, const float* __restrict__ w3z,
    const unsigned short* __restrict__ xs, unsigned short* __restrict__ act)
{
    __shared__ unsigned char lds[2][8192];   // per buf: w1 4KB @0, w3 4KB @4096
    const int tid  = threadIdx.x;
    const int swz  = (blockIdx.x & 7) * 56 + (blockIdx.x >> 3);   // 448 = 8 XCD x 56
    const int n0   = swz * 32;
    const int wid  = tid >> 6;
    const int lane = tid & 63;
    const int lr   = lane & 15;
    const int lkb  = lane >> 4;

    // weight staging: thread -> (row 0..31, 4-int group h 0..15)
    const int row = tid >> 4, h = tid & 15;
    const int4* w1p = (const int4*)w1q + (size_t)(n0 + row) * 1024;   // + kt*16 + h
    const int4* w3p = (const int4*)w3q + (size_t)(n0 + row) * 1024;
    const float* s1p = w1s + (size_t)(n0 + row) * 64;
    const float* z1p = w1z + (size_t)(n0 + row) * 64;
    const float* s3p = w3s + (size_t)(n0 + row) * 64;
    const float* z3p = w3z + (size_t)(n0 + row) * 64;
    // conflict-free swizzled write: 16 lanes of a quarter-wave cover one 128B row
    const int wbyte = row * 128 + (((h >> 1) ^ (row & 7)) << 4) + ((h & 1) << 3);

    const unsigned char* xsb = (const unsigned char*)xs;

    f4v accg[2][2], accu[2][2];
    const f4v fz = {0.f, 0.f, 0.f, 0.f};
    #pragma unroll
    for (int i = 0; i < 2; ++i)
        #pragma unroll
        for (int j = 0; j < 2; ++j) { accg[i][j] = fz; accu[i][j] = fz; }

    auto load = [&](int kt, S1& p) {
        p.q1 = w1p[kt * 16 + h];
        p.q3 = w3p[kt * 16 + h];
        p.s1 = s1p[kt]; p.z1 = z1p[kt];
        p.s3 = s3p[kt]; p.z3 = z3p[kt];
    };
    auto store = [&](const S1& p, unsigned char* b) {
        *(s4v*)(b + wbyte)        = dq4(p.q1, p.s1, -p.z1 * p.s1);
        *(s4v*)(b + 4096 + wbyte) = dq4(p.q3, p.s3, -p.z3 * p.s3);
    };
    auto compute = [&](const unsigned char* b, int kt) {
        #pragma unroll
        for (int kf = 0; kf < 2; ++kf) {
            const int sw = kf * 4 + lkb;
            s8v a[2], b1[2], b3[2];
            #pragma unroll
            for (int nf = 0; nf < 2; ++nf) {
                const int rbo = (nf * 16 + lr) * 128 + ((sw ^ (lr & 7)) << 4);
                b1[nf] = *(const s8v*)(b + rbo);
                b3[nf] = *(const s8v*)(b + 4096 + rbo);
            }
            #pragma unroll
            for (int mf = 0; mf < 2; ++mf)
                a[mf] = *(const s8v*)(xsb + (size_t)(wid * 32 + mf * 16 + lr) * 8192
                                          + kt * 128 + kf * 64 + lkb * 16);
            #pragma unroll
            for (int mf = 0; mf < 2; ++mf)
                #pragma unroll
                for (int nf = 0; nf < 2; ++nf) {
                    accg[mf][nf] = __builtin_amdgcn_mfma_f32_16x16x32_bf16(a[mf], b1[nf], accg[mf][nf], 0, 0, 0);
                    accu[mf][nf] = __builtin_amdgcn_mfma_f32_16x16x32_bf16(a[mf], b3[nf], accu[mf][nf], 0, 0, 0);
                }
        }
    };

    S1 A, B;
    load(0, A);
    store(A, lds[0]);
    load(1, B);
    bar_write();

    for (int it = 0; it < 32; ++it) {
        const int t = it * 2;
        load(t + 2 > 63 ? 63 : t + 2, A);   // prefetch, stays in flight across barriers
        compute(lds[0], t);
        bar_read();
        store(B, lds[1]);                   // counted-vmcnt wait on B's loads only
        bar_write();
        load(t + 3 > 63 ? 63 : t + 3, B);
        compute(lds[1], t + 1);
        bar_read();
        store(A, lds[0]);
        bar_write();
    }

    // epilogue: act[m][n0+n] = silu(g)*u, bf16 row-major [256][14336]
    unsigned char* actb = (unsigned char*)act;
    #pragma unroll
    for (int mf = 0; mf < 2; ++mf)
        #pragma unroll
        for (int nf = 0; nf < 2; ++nf)
            #pragma unroll
            for (int r = 0; r < 4; ++r) {
                const int m = wid * 32 + mf * 16 + lkb * 4 + r;
                const int n = n0 + nf * 16 + lr;
                float g = accg[mf][nf][r];
                float u = accu[mf][nf][r];
                float sg = g / (1.0f + __expf(-g));
                *(unsigned short*)(actb + (size_t)m * (I_DIM * 2) + n * 2) = f2bf(sg * u);
            }
}

// ---------------------------------------------------------------------------
// k_gemm2: out_partial[kc] = act[:, kc-chunk] @ w2[:, kc-chunk]^T.
// BM=256, BN=32, 4 K-chunks x 56 tiles; grid 512 (XCD-chunked swizzle so each
// kc's act slice (1.75MB) stays in 2 XCDs' L2). A (act) from global.
// ---------------------------------------------------------------------------
struct S2 { int4 q2; float s2, z2; };

template<bool ATOMIC>
__global__ __launch_bounds__(512, 4) void k_gemm2(
    const int* __restrict__ w2q, const float* __restrict__ w2s, const float* __restrict__ w2z,
    const unsigned short* __restrict__ act, float* __restrict__ outp)
{
    __shared__ unsigned char lds[2][4096];   // per buf: w2 4KB
    const int tid  = threadIdx.x;
    const int swz  = (blockIdx.x & 7) * 64 + (blockIdx.x >> 3);   // 512 = 8 x 64
    const int kc   = swz >> 7;               // 0..3
    const int nb   = swz & 127;              // 0..127
    const int n0   = nb * 32;
    const int wid  = tid >> 6;
    const int lane = tid & 63;
    const int lr   = lane & 15;
    const int lkb  = lane >> 4;

    const int row = tid >> 4, h = tid & 15;
    const int4* w2p = (const int4*)w2q + (size_t)(n0 + row) * 3584 + (size_t)kc * 896;
    const float* s2p = w2s + (size_t)(n0 + row) * 224 + kc * 56;
    const float* z2p = w2z + (size_t)(n0 + row) * 224 + kc * 56;
    const int wbyte = row * 128 + (((h >> 1) ^ (row & 7)) << 4) + ((h & 1) << 3);

    const unsigned char* actb = (const unsigned char*)act;
    const size_t akc = (size_t)kc * 7168;    // byte offset of k-chunk within a row

    f4v acc[2][2];
    const f4v fz = {0.f, 0.f, 0.f, 0.f};
    #pragma unroll
    for (int i = 0; i < 2; ++i) { acc[i][0] = fz; acc[i][1] = fz; }

    auto load = [&](int kt, S2& p) {
        p.q2 = w2p[kt * 16 + h];
        p.s2 = s2p[kt]; p.z2 = z2p[kt];
    };
    auto store = [&](const S2& p, unsigned char* b) {
        *(s4v*)(b + wbyte) = dq4(p.q2, p.s2, -p.z2 * p.s2);
    };
    auto compute = [&](const unsigned char* b, int kt) {
        #pragma unroll
        for (int kf = 0; kf < 2; ++kf) {
            const int sw = kf * 4 + lkb;
            s8v a[2], b2[2];
            #pragma unroll
            for (int nf = 0; nf < 2; ++nf)
                b2[nf] = *(const s8v*)(b + (nf * 16 + lr) * 128 + ((sw ^ (lr & 7)) << 4));
            #pragma unroll
            for (int mf = 0; mf < 2; ++mf)
                a[mf] = *(const s8v*)(actb + (size_t)(wid * 32 + mf * 16 + lr) * (I_DIM * 2)
                                          + akc + kt * 128 + kf * 64 + lkb * 16);
            #pragma unroll
            for (int mf = 0; mf < 2; ++mf)
                #pragma unroll
                for (int nf = 0; nf < 2; ++nf)
                    acc[mf][nf] = __builtin_amdgcn_mfma_f32_16x16x32_bf16(a[mf], b2[nf], acc[mf][nf], 0, 0, 0);
        }
    };

    S2 A, B;
    load(0, A);
    store(A, lds[0]);
    load(1, B);
    bar_write();

    for (int it = 0; it < 28; ++it) {
        const int t = it * 2;
        load(t + 2 > 55 ? 55 : t + 2, A);
        compute(lds[0], t);
        bar_read();
        store(B, lds[1]);
        bar_write();
        load(t + 3 > 55 ? 55 : t + 3, B);
        compute(lds[1], t + 1);
        bar_read();
        store(A, lds[0]);
        bar_write();
    }

    float* pout = outp + (ATOMIC ? 0 : (size_t)kc * ((size_t)T_DIM * H_DIM));
    #pragma unroll
    for (int mf = 0; mf < 2; ++mf)
        #pragma unroll
        for (int nf = 0; nf < 2; ++nf)
            #pragma unroll
            for (int r = 0; r < 4; ++r) {
                const int m = wid * 32 + mf * 16 + lkb * 4 + r;
                const int n = n0 + nf * 16 + lr;
                if (ATOMIC) atomicAdd(&outp[(size_t)m * H_DIM + n], acc[mf][nf][r]);
                else        pout[(size_t)m * H_DIM + n] = acc[mf][nf][r];
            }
}

__global__ __launch_bounds__(256) void k_reduce(const f4v* __restrict__ p,
                                                f4v* __restrict__ o) {
    int i = blockIdx.x * 256 + threadIdx.x;   // 262144 f4 groups
    f4v s = p[i];
    #pragma unroll
    for (int c = 1; c < 4; ++c) s += p[(size_t)c * 262144 + i];
    o[i] = s;
}

__global__ __launch_bounds__(256) void k_zero(f4v* __restrict__ o) {
    o[blockIdx.x * 256 + threadIdx.x] = (f4v){0.f, 0.f, 0.f, 0.f};
}

extern "C" void kernel_launch(void* const* d_in, const int* in_sizes, int n_in,
                              void* d_out, int out_size, void* d_ws, size_t ws_size,
                              hipStream_t stream) {
    const float* x   = (const float*)d_in[0];
    const int*   w1q = (const int*)  d_in[1];
    const float* w1s = (const float*)d_in[2];
    const float* w1z = (const float*)d_in[3];
    const int*   w3q = (const int*)  d_in[4];
    const float* w3s = (const float*)d_in[5];
    const float* w3z = (const float*)d_in[6];
    const int*   w2q = (const int*)  d_in[7];
    const float* w2s = (const float*)d_in[8];
    const float* w2z = (const float*)d_in[9];
    float* outp = (float*)d_out;

    unsigned short* xs  = (unsigned short*)d_ws;
    unsigned short* act = (unsigned short*)((char*)d_ws + ACT_OFF);
    float*          prt = (float*)((char*)d_ws + PART_OFF);
    const bool partials = (ws_size >= WS_NEEDED);

    k_prep<<<512, 256, 0, stream>>>(x, xs);
    k_gemm1<<<448, 512, 0, stream>>>(w1q, w1s, w1z, w3q, w3s, w3z, xs, act);
    if (partials) {
        k_gemm2<false><<<512, 512, 0, stream>>>(w2q, w2s, w2z, act, prt);
        k_reduce<<<1024, 256, 0, stream>>>((const f4v*)prt, (f4v*)outp);
    } else {
        k_zero<<<1024, 256, 0, stream>>>((f4v*)outp);
        k_gemm2<true><<<512, 512, 0, stream>>>(w2q, w2s, w2z, act, outp);
    }
}

// Round 5
// 297.844 us; speedup vs baseline: 1.1243x; 1.1243x over previous
//
#include <hip/hip_runtime.h>
#include <cstdint>
#include <cstddef>

#define T_DIM 256
#define H_DIM 4096
#define I_DIM 14336
// GROUP_SIZE=64 == BK: one (scale,zero) per row per K-tile.

typedef __attribute__((ext_vector_type(8))) short s8v;   // 8 bf16
typedef __attribute__((ext_vector_type(4))) short s4v;   // 4 bf16
typedef __attribute__((ext_vector_type(4))) float f4v;   // MFMA C/D frag

static constexpr size_t XS_BYTES   = (size_t)T_DIM * H_DIM * 2;   // 2 MiB bf16 x (frag-major)
static constexpr size_t ACT_OFF    = XS_BYTES;
static constexpr size_t ACT_BYTES  = (size_t)T_DIM * I_DIM * 2;   // 7.34 MB bf16 act (frag-major)
static constexpr size_t PART_OFF   = ACT_OFF + ACT_BYTES;
static constexpr size_t PART_BYTES = 4ull * T_DIM * H_DIM * 4;    // 16 MiB (4 K-chunks)
static constexpr size_t WS_NEEDED  = PART_OFF + PART_BYTES;

__device__ __forceinline__ unsigned short f2bf(float f) {
    unsigned u = __builtin_bit_cast(unsigned, f);
    u += 0x7fffu + ((u >> 16) & 1u);
    return (unsigned short)(u >> 16);
}

__device__ __forceinline__ void g2lds16(const void* g, void* l) {
    __builtin_amdgcn_global_load_lds(
        (const __attribute__((address_space(1))) unsigned int*)g,
        (__attribute__((address_space(3))) unsigned int*)l,
        16, 0, 0);
}

// Barrier discipline: never drain vmcnt in the main loop.
__device__ __forceinline__ void bar_read() {
    __builtin_amdgcn_sched_barrier(0);
    __builtin_amdgcn_s_barrier();
    __builtin_amdgcn_sched_barrier(0);
}
__device__ __forceinline__ void bar_write() {
    __builtin_amdgcn_sched_barrier(0);
    asm volatile("s_waitcnt lgkmcnt(0)" ::: "memory");
    __builtin_amdgcn_s_barrier();
    __builtin_amdgcn_sched_barrier(0);
}

__device__ __forceinline__ s4v dq4(const int4 q, float s, float ns) {
    union { unsigned short u[4]; s4v v; } r;
    r.u[0] = f2bf(fmaf((float)q.x, s, ns));
    r.u[1] = f2bf(fmaf((float)q.y, s, ns));
    r.u[2] = f2bf(fmaf((float)q.z, s, ns));
    r.u[3] = f2bf(fmaf((float)q.w, s, ns));
    return r.v;
}

// ---------------------------------------------------------------------------
// k_prep: x fp32 [256,4096] -> bf16 in A-FRAGMENT-MAJOR layout:
// fragment f = ksub*16 + msub (ksub=k/32, msub=m/16), lane l holds
// x[msub*16 + (l&15)][ksub*32 + (l>>4)*8 .. +7] at byte f*1024 + l*16.
// ---------------------------------------------------------------------------
__global__ __launch_bounds__(256) void k_prep(const float* __restrict__ x,
                                              unsigned short* __restrict__ xs) {
    int t = blockIdx.x * 256 + threadIdx.x;   // 0..131071
    int l = t & 63, f = t >> 6;
    int msub = f & 15, ksub = f >> 4;
    int m = msub * 16 + (l & 15);
    int k = ksub * 32 + (l >> 4) * 8;
    const float* xp = x + (size_t)m * H_DIM + k;
    float4 a = *(const float4*)xp;
    float4 b = *(const float4*)(xp + 4);
    union { unsigned short u[8]; s8v v; } r;
    r.u[0] = f2bf(a.x); r.u[1] = f2bf(a.y); r.u[2] = f2bf(a.z); r.u[3] = f2bf(a.w);
    r.u[4] = f2bf(b.x); r.u[5] = f2bf(b.y); r.u[6] = f2bf(b.z); r.u[7] = f2bf(b.w);
    *((s8v*)xs + t) = r.v;
}

// ---------------------------------------------------------------------------
// k_gemm1: fused gate/up GEMM. BM=256(all M), BN=32, BK=64, K=4096, grid 448.
// x staged via linear global_load_lds (depth-3 ring of 4x32KB);
// weights reg-staged depth-4 (ring R0..R3), dequant->LDS dbuf (2x8KB).
// Uniform per-tile VMEM issue: 6 (weights) + 4 (g2lds) -> vmcnt(26) at compute.
// ---------------------------------------------------------------------------
struct W1R { int4 q1, q3; float s1, z1, s3, z3; };

__global__ __launch_bounds__(512) void k_gemm1(
    const int* __restrict__ w1q, const float* __restrict__ w1s, const float* __restrict__ w1z,
    const int* __restrict__ w3q, const float* __restrict__ w3s, const float* __restrict__ w3z,
    const unsigned short* __restrict__ xs, unsigned short* __restrict__ act)
{
    __shared__ unsigned char lds[147456];   // x ring 4x32768 @0; w dbuf 2x8192 @131072
    const int tid  = threadIdx.x;
    const int blk  = blockIdx.x;
    const int n0   = blk * 32;
    const int wid  = tid >> 6;
    const int lane = tid & 63;
    const int lr   = lane & 15;
    const int lkb  = lane >> 4;

    // weight staging map: row 0..31, h = 4-int group 0..15
    const int row = tid >> 4, h = tid & 15;
    const int4* w1p = (const int4*)w1q + (size_t)(n0 + row) * 1024;
    const int4* w3p = (const int4*)w3q + (size_t)(n0 + row) * 1024;
    const float* s1p = w1s + (size_t)(n0 + row) * 64;
    const float* z1p = w1z + (size_t)(n0 + row) * 64;
    const float* s3p = w3s + (size_t)(n0 + row) * 64;
    const float* z3p = w3z + (size_t)(n0 + row) * 64;
    const int wbyte = row * 128 + ((((h >> 1) ^ (row & 7)) << 4) | ((h & 1) << 3));

    const unsigned char* xsb = (const unsigned char*)xs;

    f4v accg[2][2], accu[2][2];
    const f4v fz = {0.f, 0.f, 0.f, 0.f};
    #pragma unroll
    for (int i = 0; i < 2; ++i)
        #pragma unroll
        for (int j = 0; j < 2; ++j) { accg[i][j] = fz; accu[i][j] = fz; }

    auto xl = [&](int t) -> unsigned char* { return lds + (size_t)(t & 3) * 32768; };
    auto wl = [&](int t) -> unsigned char* { return lds + 131072 + (size_t)(t & 1) * 8192; };

    auto wload = [&](int kt, W1R& p) {
        p.q1 = w1p[kt * 16 + h];
        p.q3 = w3p[kt * 16 + h];
        p.s1 = s1p[kt]; p.z1 = z1p[kt]; p.s3 = s3p[kt]; p.z3 = z3p[kt];
    };
    auto xstage = [&](int kt, unsigned char* dst) {
        const unsigned char* src = xsb + (size_t)kt * 32768 + (size_t)(wid * 4) * 1024
                                       + (size_t)lane * 16;
        #pragma unroll
        for (int j = 0; j < 4; ++j)
            g2lds16(src + j * 1024, dst + (wid * 4 + j) * 1024);
    };
    auto wstore = [&](const W1R& p, unsigned char* b) {
        *(s4v*)(b + wbyte)        = dq4(p.q1, p.s1, -p.z1 * p.s1);
        *(s4v*)(b + 4096 + wbyte) = dq4(p.q3, p.s3, -p.z3 * p.s3);
    };
    auto compute = [&](const unsigned char* xb, const unsigned char* wb) {
        #pragma unroll
        for (int kf = 0; kf < 2; ++kf) {
            s8v a[2], b1[2], b3[2];
            #pragma unroll
            for (int mf = 0; mf < 2; ++mf)
                a[mf] = *(const s8v*)(xb + (kf * 16 + wid * 2 + mf) * 1024 + lane * 16);
            #pragma unroll
            for (int nf = 0; nf < 2; ++nf) {
                const int rbo = (nf * 16 + lr) * 128 + (((kf * 4 + lkb) ^ (lr & 7)) << 4);
                b1[nf] = *(const s8v*)(wb + rbo);
                b3[nf] = *(const s8v*)(wb + 4096 + rbo);
            }
            #pragma unroll
            for (int mf = 0; mf < 2; ++mf)
                #pragma unroll
                for (int nf = 0; nf < 2; ++nf) {
                    accg[mf][nf] = __builtin_amdgcn_mfma_f32_16x16x32_bf16(a[mf], b1[nf], accg[mf][nf], 0, 0, 0);
                    accu[mf][nf] = __builtin_amdgcn_mfma_f32_16x16x32_bf16(a[mf], b3[nf], accu[mf][nf], 0, 0, 0);
                }
        }
    };

    W1R R0, R1, R2, R3;
    // prologue mimics steady-state issue pattern (keeps vmcnt(26) exact at t=0)
    wload(0, R0);
    wload(1, R1); xstage(0, xl(0));
    wload(2, R2); xstage(1, xl(1));
    wload(3, R3); xstage(2, xl(2));
    wstore(R0, wl(0));
    bar_write();

    auto step = [&](int t, W1R& Rld, const W1R& Rst) {
        wload((t + 4) & 63, Rld);               // 6 VMEM, depth-4
        __builtin_amdgcn_sched_barrier(0);
        xstage((t + 3) & 63, xl(t + 3));        // 4 g2lds, depth-3
        __builtin_amdgcn_sched_barrier(0);
        asm volatile("s_waitcnt vmcnt(26)" ::: "memory");   // x(t) landed; weights stay in flight
        __builtin_amdgcn_sched_barrier(0);
        compute(xl(t), wl(t));                  // pure LDS + MFMA
        bar_read();
        wstore(Rst, wl(t + 1));                 // compiler-counted wait on 4-tile-old regs
        bar_write();
    };
    for (int i = 0; i < 16; ++i) {
        const int t = i * 4;
        step(t + 0, R0, R1);
        step(t + 1, R1, R2);
        step(t + 2, R2, R3);
        step(t + 3, R3, R0);
    }

    // epilogue: act in A2-fragment-major layout (ksub = blk)
    unsigned char* actb = (unsigned char*)act;
    #pragma unroll
    for (int mf = 0; mf < 2; ++mf) {
        const int msub = wid * 2 + mf;
        #pragma unroll
        for (int nf = 0; nf < 2; ++nf)
            #pragma unroll
            for (int r = 0; r < 4; ++r) {
                const int mrow  = lkb * 4 + r;
                const int n     = nf * 16 + lr;            // 0..31 within ksub
                const int lanef = mrow + (n >> 3) * 16;
                float g = accg[mf][nf][r];
                float u = accu[mf][nf][r];
                float sg = g / (1.0f + __expf(-g));
                *(unsigned short*)(actb + (size_t)(blk * 16 + msub) * 1024
                                        + lanef * 16 + (n & 7) * 2) = f2bf(sg * u);
            }
    }
}

// ---------------------------------------------------------------------------
// k_gemm2: out_partial[kc] = act[:, kc-chunk] @ w2[:, kc-chunk]^T.
// BM=256, BN=32, 4 K-chunks x 56 tiles; grid 512, kc packed per XCD-pair.
// Same pipeline; per-tile VMEM = 3 + 4 -> vmcnt(17).
// ---------------------------------------------------------------------------
struct W2R { int4 q2; float s2, z2; };

template<bool ATOMIC>
__global__ __launch_bounds__(512) void k_gemm2(
    const int* __restrict__ w2q, const float* __restrict__ w2s, const float* __restrict__ w2z,
    const unsigned short* __restrict__ act, float* __restrict__ outp)
{
    __shared__ unsigned char lds[139264];   // act ring 4x32768 @0; w2 dbuf 2x4096 @131072
    const int tid  = threadIdx.x;
    const int bx   = blockIdx.x;
    const int kc   = (bx & 7) >> 1;          // K-chunk per XCD-pair (L2 locality for act)
    const int nb   = (bx >> 3) * 2 + (bx & 1);
    const int n0   = nb * 32;
    const int wid  = tid >> 6;
    const int lane = tid & 63;
    const int lr   = lane & 15;
    const int lkb  = lane >> 4;

    const int row = tid >> 4, h = tid & 15;
    const int4* w2p = (const int4*)w2q + (size_t)(n0 + row) * 3584;
    const float* s2p = w2s + (size_t)(n0 + row) * 224;
    const float* z2p = w2z + (size_t)(n0 + row) * 224;
    const int wbyte = row * 128 + ((((h >> 1) ^ (row & 7)) << 4) | ((h & 1) << 3));

    const unsigned char* actb = (const unsigned char*)act;
    const int kt0 = kc * 56;

    f4v acc[2][2];
    const f4v fz = {0.f, 0.f, 0.f, 0.f};
    #pragma unroll
    for (int i = 0; i < 2; ++i) { acc[i][0] = fz; acc[i][1] = fz; }

    auto xl = [&](int t) -> unsigned char* { return lds + (size_t)(t & 3) * 32768; };
    auto wl = [&](int t) -> unsigned char* { return lds + 131072 + (size_t)(t & 1) * 4096; };
    auto wrap = [](int v) { return v >= 56 ? v - 56 : v; };

    auto wload = [&](int ktL, W2R& p) {
        const int ktg = kt0 + ktL;
        p.q2 = w2p[ktg * 16 + h];
        p.s2 = s2p[ktg]; p.z2 = z2p[ktg];
    };
    auto xstage = [&](int ktL, unsigned char* dst) {
        const unsigned char* src = actb + (size_t)(kt0 + ktL) * 32768
                                        + (size_t)(wid * 4) * 1024 + (size_t)lane * 16;
        #pragma unroll
        for (int j = 0; j < 4; ++j)
            g2lds16(src + j * 1024, dst + (wid * 4 + j) * 1024);
    };
    auto wstore = [&](const W2R& p, unsigned char* b) {
        *(s4v*)(b + wbyte) = dq4(p.q2, p.s2, -p.z2 * p.s2);
    };
    auto compute = [&](const unsigned char* xb, const unsigned char* wb) {
        #pragma unroll
        for (int kf = 0; kf < 2; ++kf) {
            s8v a[2], b2[2];
            #pragma unroll
            for (int mf = 0; mf < 2; ++mf)
                a[mf] = *(const s8v*)(xb + (kf * 16 + wid * 2 + mf) * 1024 + lane * 16);
            #pragma unroll
            for (int nf = 0; nf < 2; ++nf)
                b2[nf] = *(const s8v*)(wb + (nf * 16 + lr) * 128
                                          + (((kf * 4 + lkb) ^ (lr & 7)) << 4));
            #pragma unroll
            for (int mf = 0; mf < 2; ++mf)
                #pragma unroll
                for (int nf = 0; nf < 2; ++nf)
                    acc[mf][nf] = __builtin_amdgcn_mfma_f32_16x16x32_bf16(a[mf], b2[nf], acc[mf][nf], 0, 0, 0);
        }
    };

    W2R R0, R1, R2, R3;
    wload(0, R0);
    wload(1, R1); xstage(0, xl(0));
    wload(2, R2); xstage(1, xl(1));
    wload(3, R3); xstage(2, xl(2));
    wstore(R0, wl(0));
    bar_write();

    auto step = [&](int t, W2R& Rld, const W2R& Rst) {
        wload(wrap(t + 4), Rld);
        __builtin_amdgcn_sched_barrier(0);
        xstage(wrap(t + 3), xl(t + 3));
        __builtin_amdgcn_sched_barrier(0);
        asm volatile("s_waitcnt vmcnt(17)" ::: "memory");
        __builtin_amdgcn_sched_barrier(0);
        compute(xl(t), wl(t));
        bar_read();
        wstore(Rst, wl(t + 1));
        bar_write();
    };
    for (int i = 0; i < 14; ++i) {
        const int t = i * 4;
        step(t + 0, R0, R1);
        step(t + 1, R1, R2);
        step(t + 2, R2, R3);
        step(t + 3, R3, R0);
    }

    float* pout = outp + (ATOMIC ? 0 : (size_t)kc * ((size_t)T_DIM * H_DIM));
    #pragma unroll
    for (int mf = 0; mf < 2; ++mf)
        #pragma unroll
        for (int nf = 0; nf < 2; ++nf)
            #pragma unroll
            for (int r = 0; r < 4; ++r) {
                const int m = wid * 32 + mf * 16 + lkb * 4 + r;
                const int n = n0 + nf * 16 + lr;
                if (ATOMIC) atomicAdd(&outp[(size_t)m * H_DIM + n], acc[mf][nf][r]);
                else        pout[(size_t)m * H_DIM + n] = acc[mf][nf][r];
            }
}

__global__ __launch_bounds__(256) void k_reduce(const f4v* __restrict__ p,
                                                f4v* __restrict__ o) {
    int i = blockIdx.x * 256 + threadIdx.x;   // 262144 f4 groups
    f4v s = p[i];
    #pragma unroll
    for (int c = 1; c < 4; ++c) s += p[(size_t)c * 262144 + i];
    o[i] = s;
}

__global__ __launch_bounds__(256) void k_zero(f4v* __restrict__ o) {
    o[blockIdx.x * 256 + threadIdx.x] = (f4v){0.f, 0.f, 0.f, 0.f};
}

extern "C" void kernel_launch(void* const* d_in, const int* in_sizes, int n_in,
                              void* d_out, int out_size, void* d_ws, size_t ws_size,
                              hipStream_t stream) {
    const float* x   = (const float*)d_in[0];
    const int*   w1q = (const int*)  d_in[1];
    const float* w1s = (const float*)d_in[2];
    const float* w1z = (const float*)d_in[3];
    const int*   w3q = (const int*)  d_in[4];
    const float* w3s = (const float*)d_in[5];
    const float* w3z = (const float*)d_in[6];
    const int*   w2q = (const int*)  d_in[7];
    const float* w2s = (const float*)d_in[8];
    const float* w2z = (const float*)d_in[9];
    float* outp = (float*)d_out;

    unsigned short* xs  = (unsigned short*)d_ws;
    unsigned short* act = (unsigned short*)((char*)d_ws + ACT_OFF);
    float*          prt = (float*)((char*)d_ws + PART_OFF);
    const bool partials = (ws_size >= WS_NEEDED);

    k_prep<<<512, 256, 0, stream>>>(x, xs);
    k_gemm1<<<448, 512, 0, stream>>>(w1q, w1s, w1z, w3q, w3s, w3z, xs, act);
    if (partials) {
        k_gemm2<false><<<512, 512, 0, stream>>>(w2q, w2s, w2z, act, prt);
        k_reduce<<<1024, 256, 0, stream>>>((const f4v*)prt, (f4v*)outp);
    } else {
        k_zero<<<1024, 256, 0, stream>>>((f4v*)outp);
        k_gemm2<true><<<512, 512, 0, stream>>>(w2q, w2s, w2z, act, outp);
    }
}